// Round 6
// baseline (630.994 us; speedup 1.0000x reference)
//
#include <hip/hip_runtime.h>

#define T_   2048
#define D_   256
#define N_   512
#define BTOT 16

typedef unsigned short ushortT;

// fp32 output layout (out_size = 8,421,377 floats):
//   [0, 8388608)  quantize (B,T,D) ; [8388608] diff ; [8388609, +B*T) indices
#define QN   ((size_t)BTOT*T_*D_)
#define IDX0 (QN + 1)

__device__ __forceinline__ float bf2f(ushortT u){
    union { unsigned int i; float f; } c; c.i = ((unsigned int)u) << 16; return c.f;
}
__device__ __forceinline__ void unp8(uint4 p, float* f){
    f[0]=bf2f((ushortT)(p.x & 0xffff)); f[1]=bf2f((ushortT)(p.x >> 16));
    f[2]=bf2f((ushortT)(p.y & 0xffff)); f[3]=bf2f((ushortT)(p.y >> 16));
    f[4]=bf2f((ushortT)(p.z & 0xffff)); f[5]=bf2f((ushortT)(p.z >> 16));
    f[6]=bf2f((ushortT)(p.w & 0xffff)); f[7]=bf2f((ushortT)(p.w >> 16));
}
__device__ __forceinline__ void unp4(uint2 p, float* f){
    f[0]=bf2f((ushortT)(p.x & 0xffff)); f[1]=bf2f((ushortT)(p.x >> 16));
    f[2]=bf2f((ushortT)(p.y & 0xffff)); f[3]=bf2f((ushortT)(p.y >> 16));
}

// ---- dtype probe: bf16 vs fp32 input buffers ------------------------------
__global__ void k_probe(const ushortT* __restrict__ x, int* __restrict__ flg){
    int tid = threadIdx.x;
    ushortT u = x[tid];
    int e = (u >> 7) & 0xff;
    bool ok = (e >= 100 && e <= 140);
    unsigned long long m = __ballot(ok);
    if (tid == 0) *flg = (__popcll(m) >= 55) ? 1 : 0;
}

// ---- K1: codebook build for b in [b0, b0+BC) ------------------------------
template<int BC>
__global__ __launch_bounds__(256) void k_codebook(
    const void* __restrict__ spkin, const void* __restrict__ embin,
    float* __restrict__ cbw, int b0, const int* __restrict__ flagp)
{
    const int isb = *flagp;
    const ushortT* ss = (const ushortT*)spkin;
    const float*   sf = (const float*)spkin;
    const ushortT* es = (const ushortT*)embin;
    const float*   ef = (const float*)embin;

    __shared__ float s2[D_ * 16];
    __shared__ float s1[D_ * 16];
    __shared__ float red[16 * D_];
    __shared__ float nrm[16];

    const int n = blockIdx.x, tid = threadIdx.x;

    for (int e = tid; e < D_ * 16; e += 256){ s2[e] = 0.f; s1[e] = 0.f; }
    __syncthreads();
    for (int e = tid; e < D_ * BC; e += 256){
        int bl = e >> 8, k = e & 255;
        int g2 = (2*BTOT + b0 + bl)*D_ + k;
        int g1 = (1*BTOT + b0 + bl)*D_ + k;
        s2[k*16 + bl] = isb ? bf2f(ss[g2]) : sf[g2];
        s1[k*16 + bl] = isb ? bf2f(ss[g1]) : sf[g1];
    }
    __syncthreads();

    const int d = tid;
    float acc[16];
    #pragma unroll
    for (int b = 0; b < 16; b++) acc[b] = 0.f;

    const size_t rb = ((size_t)n * D_ + d) * D_;

    auto inner = [&](const float* ev, int k0){
        #pragma unroll
        for (int j = 0; j < 8; j++){
            float e = ev[j];
            if (BC == 16){
                const float4* sp = (const float4*)&s2[(k0 + j) * 16];
                float4 q0 = sp[0], q1 = sp[1], q2 = sp[2], q3 = sp[3];
                acc[0]  += e*q0.x; acc[1]  += e*q0.y; acc[2]  += e*q0.z; acc[3]  += e*q0.w;
                acc[4]  += e*q1.x; acc[5]  += e*q1.y; acc[6]  += e*q1.z; acc[7]  += e*q1.w;
                acc[8]  += e*q2.x; acc[9]  += e*q2.y; acc[10] += e*q2.z; acc[11] += e*q2.w;
                acc[12] += e*q3.x; acc[13] += e*q3.y; acc[14] += e*q3.z; acc[15] += e*q3.w;
            } else {
                #pragma unroll
                for (int bl = 0; bl < BC; bl++)
                    acc[bl] += e * s2[(k0 + j)*16 + bl];
            }
        }
    };

    if (isb){
        for (int k0 = 0; k0 < D_; k0 += 8){
            uint4 p = *(const uint4*)(es + rb + k0);
            float ev[8]; unp8(p, ev);
            inner(ev, k0);
        }
    } else {
        for (int k0 = 0; k0 < D_; k0 += 8){
            float4 p0 = *(const float4*)(ef + rb + k0);
            float4 p1 = *(const float4*)(ef + rb + k0 + 4);
            float ev[8] = {p0.x,p0.y,p0.z,p0.w,p1.x,p1.y,p1.z,p1.w};
            inner(ev, k0);
        }
    }

    #pragma unroll
    for (int bl = 0; bl < BC; bl++) red[bl*D_ + d] = acc[bl]*acc[bl];
    __syncthreads();
    for (int s = 128; s > 0; s >>= 1){
        if (d < s){
            #pragma unroll
            for (int bl = 0; bl < BC; bl++) red[bl*D_ + d] += red[bl*D_ + d + s];
        }
        __syncthreads();
    }
    if (d < BC) nrm[d] = sqrtf(red[d*D_]);
    __syncthreads();

    #pragma unroll
    for (int bl = 0; bl < BC; bl++){
        float cb = acc[bl] / nrm[bl] + s1[d*16 + bl];
        cbw[((size_t)bl*N_ + n)*D_ + d] = cb;
    }
}

// ---- K2: scores GEMM (128 rows x full 512 n) + argmin + fused gather ------
// grid Bc*16 blocks: (bl, tT); 512 threads; micro-tile 8x16; K=256.
// e2 computed as two half-sums (k 0-7 / 8-15 per chunk) added once at use —
// bit-exact with the round-4 kernel that validated on this dataset. Do not
// reorder: argmin rows are knife-edge (min top-2 gap ~3e-4 over 32768 rows).
__global__ __launch_bounds__(512, 2) void k_gemm(
    const void* __restrict__ xin, const float* __restrict__ cbw,
    float* __restrict__ outf, float* __restrict__ part,
    int blk0, const int* __restrict__ flagp)
{
    const int isb = *flagp;
    const int bl = blockIdx.x >> 4, tT = blockIdx.x & 15;
    const int bg = blk0 + bl;

    __shared__ float As[16 * 132];   // [k][row], stride 132: staging writes 2-way max
    __shared__ float Bs[16 * 512];   // [k][n]
    __shared__ float e2p[1024];      // [n][half] partial |e_n|^2
    __shared__ int   sidx[128];      // per-row winner
    __shared__ float wred[8];

    const int tid = threadIdx.x;
    const int tx = tid & 31, ty = tid >> 5;     // micro-tile coords
    const int rA = tid >> 2, qA = tid & 3;      // A staging: row, k-quarter

    const float*   xf = (const float*)xin;
    const ushortT* xs = (const ushortT*)xin;
    const size_t xbase = ((size_t)bg*T_ + tT*128 + rA)*D_ + qA*4;
    const size_t bbase = ((size_t)bl*N_ + tid)*D_;

    float acc[8][16];
    #pragma unroll
    for (int i = 0; i < 8; i++)
        #pragma unroll
        for (int j = 0; j < 16; j++) acc[i][j] = 0.f;
    float e2lo = 0.f, e2hi = 0.f;

    // preload chunk k0=0 into registers
    float av[4], bv[16];
    {
        if (isb){ uint2 p = *(const uint2*)(xs + xbase); unp4(p, av); }
        else    { float4 p = *(const float4*)(xf + xbase);
                  av[0]=p.x; av[1]=p.y; av[2]=p.z; av[3]=p.w; }
        #pragma unroll
        for (int q = 0; q < 4; q++){
            float4 c = *(const float4*)(cbw + bbase + q*4);
            bv[q*4+0]=c.x; bv[q*4+1]=c.y; bv[q*4+2]=c.z; bv[q*4+3]=c.w;
        }
    }

    for (int k0 = 0; k0 < D_; k0 += 16){
        // stage current chunk
        #pragma unroll
        for (int j = 0; j < 4; j++) As[(qA*4 + j)*132 + rA] = av[j];
        #pragma unroll
        for (int k = 0; k < 16; k++) Bs[k*512 + tid] = bv[k];
        #pragma unroll
        for (int k = 0; k < 8; k++)  e2lo += bv[k]*bv[k];      // round-4 half-sum order
        #pragma unroll
        for (int k = 8; k < 16; k++) e2hi += bv[k]*bv[k];
        __syncthreads();

        // prefetch next chunk (overlaps the 16-kl compute below)
        if (k0 + 16 < D_){
            if (isb){ uint2 p = *(const uint2*)(xs + xbase + k0 + 16); unp4(p, av); }
            else    { float4 p = *(const float4*)(xf + xbase + k0 + 16);
                      av[0]=p.x; av[1]=p.y; av[2]=p.z; av[3]=p.w; }
            #pragma unroll
            for (int q = 0; q < 4; q++){
                float4 c = *(const float4*)(cbw + bbase + k0 + 16 + q*4);
                bv[q*4+0]=c.x; bv[q*4+1]=c.y; bv[q*4+2]=c.z; bv[q*4+3]=c.w;
            }
        }

        #pragma unroll
        for (int kl = 0; kl < 16; kl++){
            float4 a0 = *(const float4*)&As[kl*132 + (ty<<2)];          // broadcast
            float4 a1 = *(const float4*)&As[kl*132 + 64 + (ty<<2)];     // broadcast
            float4 c0 = *(const float4*)&Bs[kl*512 + (tx<<2)];
            float4 c1 = *(const float4*)&Bs[kl*512 + 128 + (tx<<2)];
            float4 c2 = *(const float4*)&Bs[kl*512 + 256 + (tx<<2)];
            float4 c3 = *(const float4*)&Bs[kl*512 + 384 + (tx<<2)];
            float ar[8]  = {a0.x,a0.y,a0.z,a0.w,a1.x,a1.y,a1.z,a1.w};
            float br[16] = {c0.x,c0.y,c0.z,c0.w,c1.x,c1.y,c1.z,c1.w,
                            c2.x,c2.y,c2.z,c2.w,c3.x,c3.y,c3.z,c3.w};
            #pragma unroll
            for (int i = 0; i < 8; i++)
                #pragma unroll
                for (int j = 0; j < 16; j++)
                    acc[i][j] += ar[i]*br[j];
        }
        __syncthreads();
    }

    e2p[tid*2]     = e2lo;    // [n][half] layout, matches round-4 bit-exactly
    e2p[tid*2 + 1] = e2hi;
    __syncthreads();

    // scores + per-thread argmin over this thread's 16 columns
    float runv[8]; int runi[8];
    #pragma unroll
    for (int i = 0; i < 8; i++){ runv[i] = 3.4e38f; runi[i] = 0x7fffffff; }
    #pragma unroll
    for (int j = 0; j < 16; j++){
        int col = ((j>>2)<<7) + (tx<<2) + (j&3);
        float e2c = e2p[col*2] + e2p[col*2 + 1];
        #pragma unroll
        for (int i = 0; i < 8; i++){
            float s = e2c - 2.f*acc[i][j];
            if (s < runv[i] || (s == runv[i] && col < runi[i])){
                runv[i] = s; runi[i] = col;
            }
        }
    }
    // reduce across the 32 tx lanes (xor masks stay within each 32-lane half)
    #pragma unroll
    for (int m = 16; m >= 1; m >>= 1){
        #pragma unroll
        for (int i = 0; i < 8; i++){
            float ov = __shfl_xor(runv[i], m);
            int   on = __shfl_xor(runi[i], m);
            if (ov < runv[i] || (ov == runv[i] && on < runi[i])){
                runv[i] = ov; runi[i] = on;
            }
        }
    }
    if (tx == 0){
        #pragma unroll
        for (int i = 0; i < 8; i++){
            int row = (ty<<2) + (i&3) + ((i>>2)<<6);
            sidx[row] = runi[i];
            outf[IDX0 + (size_t)bg*T_ + tT*128 + row] = (float)runi[i];
        }
    }
    __syncthreads();

    // fused gather: 8 rows per iter (one row per 64-lane group), float4 per lane
    const int d4 = (tid & 63) << 2;
    const int rg = tid >> 6;
    float dacc = 0.f;
    #pragma unroll 4
    for (int it = 0; it < 16; it++){
        int r = it*8 + rg;
        int n = sidx[r];                                 // wave-uniform
        size_t xrow = ((size_t)bg*T_ + tT*128 + r)*D_ + d4;
        float xv[4];
        if (isb){ uint2 p = *(const uint2*)(xs + xrow); unp4(p, xv); }
        else    { float4 p = *(const float4*)(xf + xrow);
                  xv[0]=p.x; xv[1]=p.y; xv[2]=p.z; xv[3]=p.w; }
        float4 q = *(const float4*)(cbw + ((size_t)bl*N_ + n)*D_ + d4);
        float m0 = q.x - xv[0], m1 = q.y - xv[1], m2 = q.z - xv[2], m3 = q.w - xv[3];
        float4 o;
        o.x = 0.5f*(q.x + (xv[0] + m0));
        o.y = 0.5f*(q.y + (xv[1] + m1));
        o.z = 0.5f*(q.z + (xv[2] + m2));
        o.w = 0.5f*(q.w + (xv[3] + m3));
        *(float4*)(outf + xrow) = o;
        dacc += m0*m0 + m1*m1 + m2*m2 + m3*m3;
    }
    #pragma unroll
    for (int o = 32; o > 0; o >>= 1) dacc += __shfl_down(dacc, o, 64);
    if ((tid & 63) == 0) wred[tid >> 6] = dacc;
    __syncthreads();
    if (tid == 0){
        float s = 0.f;
        #pragma unroll
        for (int w = 0; w < 8; w++) s += wred[w];
        atomicAdd(&part[blockIdx.x & 1023], s);
    }
}

// ---- K4: finalize diff (sum 1024 partials) --------------------------------
__global__ __launch_bounds__(256) void k_fin(const float* __restrict__ part,
                                             float* __restrict__ outf){
    const int tid = threadIdx.x;
    float v = part[tid] + part[tid + 256] + part[tid + 512] + part[tid + 768];
    #pragma unroll
    for (int o = 32; o > 0; o >>= 1) v += __shfl_down(v, o, 64);
    __shared__ float wsum[4];
    if ((tid & 63) == 0) wsum[tid >> 6] = v;
    __syncthreads();
    if (tid == 0)
        outf[QN] = (wsum[0] + wsum[1] + wsum[2] + wsum[3]) * (1.0f / (float)QN);
}

extern "C" void kernel_launch(void* const* d_in, const int* in_sizes, int n_in,
                              void* d_out, int out_size, void* d_ws, size_t ws_size,
                              hipStream_t stream)
{
    const void* x   = d_in[0];
    const void* spk = d_in[1];
    const void* emb = d_in[2];

    int Bc = 16;
    while (Bc > 1 && ((size_t)Bc*N_*D_*4 + 4096 + 16) > ws_size) Bc >>= 1;

    char*  ws   = (char*)d_ws;
    float* cbw  = (float*)ws;                          // Bc*512*256 fp32
    size_t tail = (size_t)Bc*N_*D_*4;
    float* part = (float*)(ws + tail);                 // 1024 floats
    int*   flg  = (int*)  (ws + tail + 4096);          // 4 B

    float* outf = (float*)d_out;

    hipMemsetAsync(part, 0, 4096, stream);
    k_probe<<<1, 64, 0, stream>>>((const ushortT*)x, flg);

    for (int b0 = 0; b0 < BTOT; b0 += Bc){
        switch (Bc){
            case 16: k_codebook<16><<<512, 256, 0, stream>>>(spk, emb, cbw, b0, flg); break;
            case 8:  k_codebook<8> <<<512, 256, 0, stream>>>(spk, emb, cbw, b0, flg); break;
            case 4:  k_codebook<4> <<<512, 256, 0, stream>>>(spk, emb, cbw, b0, flg); break;
            case 2:  k_codebook<2> <<<512, 256, 0, stream>>>(spk, emb, cbw, b0, flg); break;
            default: k_codebook<1> <<<512, 256, 0, stream>>>(spk, emb, cbw, b0, flg); break;
        }
        k_gemm<<<Bc*16, 512, 0, stream>>>(x, cbw, outf, part, b0, flg);
    }
    k_fin<<<1, 256, 0, stream>>>(part, outf);
}